// Round 9
// baseline (3340.575 us; speedup 1.0000x reference)
//
#include <hip/hip_runtime.h>
#include <hip/hip_bf16.h>
#include <stddef.h>
#include <stdint.h>

#define T_STEPS 512
#define B_SZ 256
#define H_SZ 256
#define G4H 1024
#define HS_PAR 4096  // shorts per h parity buffer (A-fragment order: 8 ks x 512)

typedef __attribute__((ext_vector_type(8))) short bf16x8;
typedef __attribute__((ext_vector_type(4))) float f32x4;

__device__ __forceinline__ unsigned short f2bf(float f) {
  union { float f; unsigned u; } v; v.f = f;
  unsigned r = v.u + 0x7fffu + ((v.u >> 16) & 1u);
  return (unsigned short)(r >> 16);
}
__device__ __forceinline__ float bf_lo(unsigned u) {
  union { unsigned u; float f; } v; v.u = u << 16; return v.f;
}
__device__ __forceinline__ float bf_hi(unsigned u) {
  union { unsigned u; float f; } v; v.u = u & 0xffff0000u; return v.f;
}
__device__ __forceinline__ float sigmoid_f(float x) {
  float e = __builtin_amdgcn_exp2f(x * -1.44269504f);
  return __builtin_amdgcn_rcpf(1.0f + e);
}
__device__ __forceinline__ float tanh_f(float x) {
  float e = __builtin_amdgcn_exp2f(x * 2.88539008f);
  return 1.0f - 2.0f * __builtin_amdgcn_rcpf(e + 1.0f);
}

// ---------------- prep ----------------
__global__ void prep_kernel(const float* __restrict__ h0, const float* __restrict__ c0,
                            const float* __restrict__ W_ih, const float* __restrict__ W_hh,
                            const float* __restrict__ b_ih, const float* __restrict__ b_hh,
                            unsigned short* __restrict__ Wih_bf, unsigned short* __restrict__ Whh_bf,
                            float* __restrict__ bias, unsigned short* __restrict__ h_st,
                            float* __restrict__ c_st) {
  int i = blockIdx.x * 256 + threadIdx.x;
  int stride = gridDim.x * 256;
  for (int k = i; k < G4H * H_SZ; k += stride) {
    Wih_bf[k] = f2bf(W_ih[k]);
    Whh_bf[k] = f2bf(W_hh[k]);
  }
  for (int k = i; k < B_SZ * H_SZ; k += stride) {
    h_st[k] = f2bf(h0[k]);
    c_st[k] = c0[k];
  }
  for (int k = i; k < G4H; k += stride) bias[k] = b_ih[k] + b_hh[k];
}

// ---------------- K1: xg = bf16( embed[idx] @ W_ih^T + bias ), gate-merged stores.
// xg layout (same as R8 consumer):
//   flat = (((t_loc*32 + bb)*16 + tau)*512) + (qt*16 + (j&15))*16 + g*4 + r
// Each wave computes ALL 4 gates for its column tiles -> each lane stores
// 16 consecutive shorts (32 B, 2 x dwordx4): full-line coalesced, one block
// per line (kills the R8 4x write amplification / cross-XCD line sharing).
// grid: Ci*4 blocks x 256 threads; wave w owns col tiles tau = w*4 + jt2.
__global__ __launch_bounds__(256) void xgate_kernel(
    const int* __restrict__ enc, const float* __restrict__ embed,
    const unsigned short* __restrict__ Wih_bf, const float* __restrict__ bias,
    unsigned short* __restrict__ xg, int t0, int Ci) {
  __shared__ __align__(16) unsigned short As[64][264];
  const int tid = threadIdx.x;
  const int mbase = blockIdx.x * 64;

  {
    int r = tid >> 2, q = tid & 3;
    int mg = mbase + r;
    int s = mg >> 8, b = mg & 255;
    int vid = enc[(t0 + s) * B_SZ + b];
    const float4* src = (const float4*)(embed + (size_t)vid * H_SZ) + q * 16;
#pragma unroll
    for (int j = 0; j < 16; ++j) {
      float4 x = src[j];
      ushort4 o;
      o.x = f2bf(x.x); o.y = f2bf(x.y); o.z = f2bf(x.z); o.w = f2bf(x.w);
      *(ushort4*)&As[r][q * 64 + j * 4] = o;
    }
  }
  __syncthreads();

  const int wave = tid >> 6, lane = tid & 63;
  const int lrow = lane & 15, quad = lane >> 4;
  const int t_loc = mbase >> 8;
  const int bloc = mbase & 255;

#pragma unroll
  for (int jt2 = 0; jt2 < 4; ++jt2) {
    const int tau = wave * 4 + jt2;
    const int j0 = tau * 16;                 // column base; col = j0 + lrow
    // B-fragments for all 4 gates of this column tile
    bf16x8 bf[4][8];
    float bs[4];
#pragma unroll
    for (int g = 0; g < 4; ++g) {
      const int nrow = g * 256 + j0 + lrow;
      const unsigned short* wrow = Wih_bf + (size_t)nrow * H_SZ + quad * 8;
#pragma unroll
      for (int ks = 0; ks < 8; ++ks) bf[g][ks] = *(const bf16x8*)(wrow + ks * 32);
      bs[g] = bias[nrow];
    }
#pragma unroll
    for (int mt = 0; mt < 4; ++mt) {
      f32x4 acc[4];
#pragma unroll
      for (int g = 0; g < 4; ++g) acc[g] = (f32x4){0.f, 0.f, 0.f, 0.f};
#pragma unroll
      for (int ks = 0; ks < 8; ++ks) {
        bf16x8 af = *(const bf16x8*)&As[mt * 16 + lrow][ks * 32 + quad * 8];
#pragma unroll
        for (int g = 0; g < 4; ++g)
          acc[g] = __builtin_amdgcn_mfma_f32_16x16x32_bf16(af, bf[g][ks], acc[g], 0, 0, 0);
      }
      const int brow = bloc + mt * 16 + quad * 4;  // batch of r=0
      const int bb = brow >> 3;
      const int qt = (brow >> 2) & 1;
      const size_t base =
          (((size_t)t_loc * 32 + bb) * 16 + tau) * 512 +
          (size_t)(qt * 16 + lrow) * 16;
      unsigned short o16[16];
#pragma unroll
      for (int g = 0; g < 4; ++g)
#pragma unroll
        for (int r = 0; r < 4; ++r) o16[g * 4 + r] = f2bf(acc[g][r] + bs[g]);
      *(uint4*)(xg + base) = *(const uint4*)&o16[0];
      *(uint4*)(xg + base + 8) = *(const uint4*)&o16[8];
    }
  }
}

// ---------------- K2: recurrent. 32 blocks x 512 threads (8 waves, 2/SIMD).
// Block owns 8 batches (M=16 padded). Wave w owns cols w*32..w*32+31 (2 tiles),
// all 4 gates. W: i,f register-resident (128 regs); g AND o streamed from L2
// (same addrs every step -> XCD-L2 resident; frees the LDS unit, which R8
// counters showed as the top structural term). Scratch re-laid-out
// (g*132 + quad*64 + lrow*4) -> 2-way banks (R8's 1083 conflict-cyc/step gone).
__global__ __launch_bounds__(512) __attribute__((amdgpu_waves_per_eu(2, 2)))
void lstm_kernel(
    const unsigned short* __restrict__ Whh_bf, const unsigned short* __restrict__ xg,
    unsigned short* __restrict__ h_st, float* __restrict__ c_st,
    float* __restrict__ out, int t0, int Ci) {
  __shared__ __align__(16) unsigned short Hs[2 * HS_PAR];  // 16 KB
  __shared__ __align__(16) float Scr[8][528];              // 16.5 KB
  // total ~33 KB static LDS

  const int tid = threadIdx.x, w = tid >> 6, lane = tid & 63;
  const int lrow = lane & 15, quad = lane >> 4;
  const int bb = blockIdx.x, b0 = bb * 8;
  const int jc0 = w * 32 + lrow, jc1 = jc0 + 16;

  // gates i,f register-resident (both tiles): 128 regs
  bf16x8 wfi[2][8], wff[2][8];
#pragma unroll
  for (int jt = 0; jt < 2; ++jt) {
    const int jc = jt ? jc1 : jc0;
    const unsigned short* wr0 = Whh_bf + (size_t)(0 * 256 + jc) * H_SZ + quad * 8;
    const unsigned short* wr1 = Whh_bf + (size_t)(1 * 256 + jc) * H_SZ + quad * 8;
#pragma unroll
    for (int ks = 0; ks < 8; ++ks) {
      wfi[jt][ks] = *(const bf16x8*)(wr0 + ks * 32);
      wff[jt][ks] = *(const bf16x8*)(wr1 + ks * 32);
    }
  }
  // gates g,o streamed from L2 every step
  const unsigned short* wrg0 = Whh_bf + (size_t)(2 * 256 + jc0) * H_SZ + quad * 8;
  const unsigned short* wrg1 = Whh_bf + (size_t)(2 * 256 + jc1) * H_SZ + quad * 8;
  const unsigned short* wro0 = Whh_bf + (size_t)(3 * 256 + jc0) * H_SZ + quad * 8;
  const unsigned short* wro1 = Whh_bf + (size_t)(3 * 256 + jc1) * H_SZ + quad * 8;

  // stage h into parity-0 (A-fragment order); zero padding rows (both parities)
  {
    int m = tid >> 5, kg = tid & 31;
    uint4 v = {0u, 0u, 0u, 0u};
    if (m < 8) v = *(const uint4*)(h_st + (size_t)(b0 + m) * H_SZ + kg * 8);
    *(uint4*)&Hs[(kg >> 2) * 512 + ((kg & 3) * 16 + m) * 8] = v;
    if (m >= 8) {
      uint4 z = {0u, 0u, 0u, 0u};
      *(uint4*)&Hs[HS_PAR + (kg >> 2) * 512 + ((kg & 3) * 16 + m) * 8] = z;
    }
  }

  float creg[2][2];
#pragma unroll
  for (int jt = 0; jt < 2; ++jt)
#pragma unroll
    for (int e = 0; e < 2; ++e)
      creg[jt][e] = c_st[(size_t)(b0 + quad * 2 + e) * H_SZ + (jt ? jc1 : jc0)];

  // xg prefetch for s=0 (quads 0,1 only)
  const size_t xg_lane = (size_t)(quad * 16 + lrow) * 16;
  uint4 xA[2][2];
  if (quad < 2) {
#pragma unroll
    for (int jt = 0; jt < 2; ++jt) {
      const unsigned short* p =
          xg + (((size_t)0 * 32 + bb) * 16 + w * 2 + jt) * 512 + xg_lane;
      xA[jt][0] = *(const uint4*)p;
      xA[jt][1] = *(const uint4*)(p + 8);
    }
  }
  __syncthreads();

  // h write address (within parity) for (m=quad*2+e, col=jc(jt)): +e*8
  const int hwb0 = w * 512 + ((0 * 2 + (lrow >> 3)) * 16 + quad * 2) * 8 + (lrow & 7);
  const int hwb1 = w * 512 + ((1 * 2 + (lrow >> 3)) * 16 + quad * 2) * 8 + (lrow & 7);
  // scratch read offset: lane (quad,lrow) reads rows m=quad*2+{0,1}, col lrow
  const int roff = (quad >> 1) * 64 + lrow * 4 + (quad & 1) * 2;

#pragma unroll 1
  for (int s = 0; s < Ci; ++s) {
    const int rp = (s & 1) * HS_PAR;
    const int wp = HS_PAR - rp;

    bf16x8 af[8];
#pragma unroll
    for (int ks = 0; ks < 8; ++ks)
      af[ks] = *(const bf16x8*)&Hs[rp + ks * 512 + lane * 8];

#pragma unroll
    for (int jt = 0; jt < 2; ++jt) {
      const unsigned short* wrg = jt ? wrg1 : wrg0;
      const unsigned short* wro = jt ? wro1 : wro0;
      f32x4 acc[4];
#pragma unroll
      for (int g = 0; g < 4; ++g) acc[g] = (f32x4){0.f, 0.f, 0.f, 0.f};
#pragma unroll
      for (int ks = 0; ks < 8; ++ks) {
        bf16x8 wg = *(const bf16x8*)(wrg + ks * 32);
        bf16x8 wo = *(const bf16x8*)(wro + ks * 32);
        acc[0] = __builtin_amdgcn_mfma_f32_16x16x32_bf16(af[ks], wfi[jt][ks], acc[0], 0, 0, 0);
        acc[1] = __builtin_amdgcn_mfma_f32_16x16x32_bf16(af[ks], wff[jt][ks], acc[1], 0, 0, 0);
        acc[2] = __builtin_amdgcn_mfma_f32_16x16x32_bf16(af[ks], wg, acc[2], 0, 0, 0);
        acc[3] = __builtin_amdgcn_mfma_f32_16x16x32_bf16(af[ks], wo, acc[3], 0, 0, 0);
      }
      // xg add (C-layout) + scratch write: real rows live in quads 0,1
      if (quad < 2) {
        unsigned xu[8];
        xu[0] = xA[jt][0].x; xu[1] = xA[jt][0].y; xu[2] = xA[jt][0].z; xu[3] = xA[jt][0].w;
        xu[4] = xA[jt][1].x; xu[5] = xA[jt][1].y; xu[6] = xA[jt][1].z; xu[7] = xA[jt][1].w;
#pragma unroll
        for (int g = 0; g < 4; ++g) {
          acc[g][0] += bf_lo(xu[g * 2]);
          acc[g][1] += bf_hi(xu[g * 2]);
          acc[g][2] += bf_lo(xu[g * 2 + 1]);
          acc[g][3] += bf_hi(xu[g * 2 + 1]);
          *(f32x4*)&Scr[w][g * 132 + quad * 64 + lrow * 4] = acc[g];
        }
      }
      // redistribution read (all lanes; per-wave in-order DS, no barrier)
      float2 gI = *(const float2*)&Scr[w][0 * 132 + roff];
      float2 gF = *(const float2*)&Scr[w][1 * 132 + roff];
      float2 gG = *(const float2*)&Scr[w][2 * 132 + roff];
      float2 gO = *(const float2*)&Scr[w][3 * 132 + roff];
      const int hwb = (jt ? hwb1 : hwb0) + wp;
#pragma unroll
      for (int e = 0; e < 2; ++e) {
        float gi = sigmoid_f(e ? gI.y : gI.x);
        float gf = sigmoid_f(e ? gF.y : gF.x);
        float gg = tanh_f(e ? gG.y : gG.x);
        float go = sigmoid_f(e ? gO.y : gO.x);
        float c = gf * creg[jt][e] + gi * gg;
        creg[jt][e] = c;
        float h = go * tanh_f(c);
        Hs[hwb + e * 8] = f2bf(h);
      }
    }
    // prefetch next step's xg
    if (quad < 2 && s + 1 < Ci) {
#pragma unroll
      for (int jt = 0; jt < 2; ++jt) {
        const unsigned short* p =
            xg + (((size_t)(s + 1) * 32 + bb) * 16 + w * 2 + jt) * 512 + xg_lane;
        xA[jt][0] = *(const uint4*)p;
        xA[jt][1] = *(const uint4*)(p + 8);
      }
    }
    __syncthreads();
  }

  // epilogue
  const int fp = (Ci & 1) * HS_PAR;
#pragma unroll
  for (int jt = 0; jt < 2; ++jt) {
    const int jc = jt ? jc1 : jc0;
    const int hwb = (jt ? hwb1 : hwb0) + fp;
#pragma unroll
    for (int e = 0; e < 2; ++e) {
      const size_t gidx = (size_t)(b0 + quad * 2 + e) * H_SZ + jc;
      unsigned short hb = Hs[hwb + e * 8];
      h_st[gidx] = hb;
      c_st[gidx] = creg[jt][e];
      if (t0 + Ci == T_STEPS) {
        out[gidx] = bf_lo((unsigned)hb);
        out[(size_t)B_SZ * H_SZ + gidx] = creg[jt][e];
      }
    }
  }
}

extern "C" void kernel_launch(void* const* d_in, const int* in_sizes, int n_in,
                              void* d_out, int out_size, void* d_ws, size_t ws_size,
                              hipStream_t stream) {
  const int* enc = (const int*)d_in[0];
  const float* h0 = (const float*)d_in[1];
  const float* c0 = (const float*)d_in[2];
  const float* embed = (const float*)d_in[3];
  const float* W_ih = (const float*)d_in[4];
  const float* W_hh = (const float*)d_in[5];
  const float* b_ih = (const float*)d_in[6];
  const float* b_hh = (const float*)d_in[7];
  float* out = (float*)d_out;

  char* ws = (char*)d_ws;
  unsigned short* Wih_bf = (unsigned short*)(ws);                  // 512 KB
  unsigned short* Whh_bf = (unsigned short*)(ws + (512 << 10));    // 512 KB
  float* bias = (float*)(ws + (1024 << 10));                       // 4 KB
  unsigned short* h_st = (unsigned short*)(ws + (1028 << 10));     // 128 KB
  float* c_st = (float*)(ws + (1156 << 10));                       // 256 KB
  const size_t fixed = (size_t)(1412) << 10;
  unsigned short* xg = (unsigned short*)(ws + fixed);

  const size_t per_step = (size_t)B_SZ * G4H * 2;  // 512 KB per timestep (bf16)
  int C = 1;
  if (ws_size > fixed + per_step) {
    size_t c = (ws_size - fixed) / per_step;
    C = (c > T_STEPS) ? T_STEPS : (int)c;
  }

  prep_kernel<<<dim3(256), dim3(256), 0, stream>>>(h0, c0, W_ih, W_hh, b_ih, b_hh,
                                                   Wih_bf, Whh_bf, bias, h_st, c_st);
  for (int t0 = 0; t0 < T_STEPS; t0 += C) {
    int Ci = (T_STEPS - t0 < C) ? (T_STEPS - t0) : C;
    xgate_kernel<<<dim3(Ci * 4), dim3(256), 0, stream>>>(enc, embed, Wih_bf, bias,
                                                         xg, t0, Ci);
    lstm_kernel<<<dim3(32), dim3(512), 0, stream>>>(Whh_bf, xg, h_st, c_st,
                                                    out, t0, Ci);
  }
}